// Round 5
// baseline (161.355 us; speedup 1.0000x reference)
//
#include <hip/hip_runtime.h>
#include <stdint.h>

typedef __attribute__((ext_vector_type(8))) short short8;
typedef __attribute__((ext_vector_type(4))) short short4v;
typedef __attribute__((ext_vector_type(4))) float float4v;
typedef unsigned short u16;

#define N_TOK 2048
#define D_MODEL 1024
#define N_HEAD 8
#define HDIM 128
#define N_BUCKET 64
#define WL_CAP 2048
#define ATTN_BLOCKS 384

__device__ __forceinline__ u16 f2bf(float f) {
  uint32_t u = __float_as_uint(f);
  uint32_t r = u + 0x7fffu + ((u >> 16) & 1u);
  return (u16)(r >> 16);
}
__device__ __forceinline__ float bf2f(u16 h) {
  return __uint_as_float(((uint32_t)h) << 16);
}

__device__ __forceinline__ void async_load16(const void* g, void* l) {
  __builtin_amdgcn_global_load_lds(
      (const __attribute__((address_space(1))) void*)g,
      (__attribute__((address_space(3))) void*)l, 16, 0, 0);
}

__device__ __forceinline__ int xcd_swz(int bid, int nwg) {
  return (bid & 7) * (nwg >> 3) + (bid >> 3);
}

// ---------- elementwise f32 -> bf16 hi + lo residual ----------
__global__ __launch_bounds__(256) void split_cast_kernel(
    const float* __restrict__ in, u16* __restrict__ hi, u16* __restrict__ lo,
    int n) {
  int i = blockIdx.x * 256 + threadIdx.x;
  if (i >= n) return;
  float v = in[i];
  u16 h = f2bf(v);
  hi[i] = h;
  if (lo) lo[i] = f2bf(v - bf2f(h));
}

// ---------- fused transpose of 4 weight matrices -> bf16 ----------
// z=0: Wq -> qkvt[0:1M]; z=1: Wk -> qkvt[1M:2M]; z=2: Wv -> qkvt[2M:3M]; z=3: Wo -> wot
__global__ __launch_bounds__(256) void transpose_all_kernel(
    const float* __restrict__ Wq, const float* __restrict__ Wk,
    const float* __restrict__ Wv, const float* __restrict__ Wo,
    u16* __restrict__ qkvt, u16* __restrict__ wot) {
  __shared__ float tile[32][33];
  const int z = blockIdx.z;
  const float* in = (z == 0) ? Wq : (z == 1) ? Wk : (z == 2) ? Wv : Wo;
  u16* hi = (z == 3) ? wot : qkvt + (size_t)z * 1024 * 1024;
  const int C = 1024, R = 1024;
  int c0 = blockIdx.x * 32, r0 = blockIdx.y * 32;
  int tx = threadIdx.x & 31, ty = threadIdx.x >> 5;
#pragma unroll
  for (int i = 0; i < 4; i++) {
    int rl = ty + i * 8;
    tile[rl][tx] = in[(size_t)(r0 + rl) * C + c0 + tx];
  }
  __syncthreads();
#pragma unroll
  for (int i = 0; i < 4; i++) {
    int cl = ty + i * 8;
    hi[(size_t)(c0 + cl) * R + r0 + tx] = f2bf(tile[tx][cl]);
  }
}

// ---------- Wqp build: Wqpt[hf][dd] = sum_dl Wq[dd][h*128+dl]*proj[h][dl][f] ----
// grid (16 rowtiles, 8 heads); also bias_sc[hf] = bq. proj (rowtile 0)
__global__ __launch_bounds__(256) void wqp_build_kernel(
    const float* __restrict__ Wq, const float* __restrict__ proj,
    const float* __restrict__ bq, u16* __restrict__ Wqpt_hi,
    u16* __restrict__ Wqpt_lo, float* __restrict__ bias_sc) {
  __shared__ float sW[64][128];
  __shared__ float sPj[128][64];
  const int tid = threadIdx.x;
  const int rt = blockIdx.x, h = blockIdx.y;
  const int dd0 = rt * 64;
#pragma unroll
  for (int p = 0; p < 8; p++) {
    int e = p * 1024 + tid * 4;
    int row = e >> 7, col = e & 127;
    *(float4v*)&sW[row][col] =
        *(const float4v*)&Wq[(size_t)(dd0 + row) * 1024 + h * HDIM + col];
    *(float4v*)&sPj[0][0 + e] = *(const float4v*)&proj[(size_t)h * (HDIM * N_BUCKET) + e];
  }
  __syncthreads();
  const int tr0 = (tid & 15) * 4, tc0 = (tid >> 4) * 4;
  float acc[4][4];
#pragma unroll
  for (int i = 0; i < 4; i++)
#pragma unroll
    for (int j = 0; j < 4; j++) acc[i][j] = 0.f;
  for (int dl = 0; dl < 128; dl++) {
    float4v pv = *(const float4v*)&sPj[dl][tc0];
#pragma unroll
    for (int i = 0; i < 4; i++) {
      float w = sW[tr0 + i][dl];
#pragma unroll
      for (int j = 0; j < 4; j++) acc[i][j] += w * pv[j];
    }
  }
#pragma unroll
  for (int j = 0; j < 4; j++) {
    short4v ph, pl;
#pragma unroll
    for (int i = 0; i < 4; i++) {
      float v = acc[i][j];
      u16 hh = f2bf(v);
      ph[i] = (short)hh;
      pl[i] = (short)f2bf(v - bf2f(hh));
    }
    size_t ofs = (size_t)(h * 64 + tc0 + j) * 1024 + dd0 + tr0;
    *(short4v*)&Wqpt_hi[ofs] = ph;
    *(short4v*)&Wqpt_lo[ofs] = pl;
  }
  if (rt == 0 && tid < 64) {
    float s = 0.f;
    for (int dl = 0; dl < 128; dl++) s += bq[h * HDIM + dl] * sPj[dl][tid];
    bias_sc[h * 64 + tid] = s;
  }
}

// ---------- fused QKV GEMM: [2048x1024]x[1024x3072] -> qbb,kbb,vbb bf16 ----
__global__ __launch_bounds__(256) void qkv_gemm_kernel(
    const u16* __restrict__ A, const u16* __restrict__ Bt,
    const float* __restrict__ bq, const float* __restrict__ bk,
    const float* __restrict__ bv, u16* __restrict__ qbb,
    u16* __restrict__ kbb, u16* __restrict__ vbb) {
  const int K = 1024;
  __shared__ __align__(16) u16 As[2][128 * 32];
  __shared__ __align__(16) u16 Bs[2][128 * 32];
  const int tid = threadIdx.x;
  const int wave = tid >> 6, lane = tid & 63;
  const int lhi = lane >> 4, llo = lane & 15;
  const int bid = xcd_swz(blockIdx.x, gridDim.x);
  const int bm = (bid / 24) << 7;
  const int bn = (bid % 24) << 7;
  const int wm = (wave >> 1) * 64;
  const int wn = (wave & 1) * 64;
  const int arow = lane >> 2;
  const int acolb = (lane & 3) * 16;

  float4v acc[4][4];
#pragma unroll
  for (int mi = 0; mi < 4; mi++)
#pragma unroll
    for (int ni = 0; ni < 4; ni++)
#pragma unroll
      for (int r = 0; r < 4; r++) acc[mi][ni][r] = 0.f;

  auto stage = [&](int b, int ko) {
#pragma unroll
    for (int cc = 0; cc < 4; cc++) {
      int idx = wave * 4 + cc;  // 0..15
      if (idx < 8) {
        int row = bm + idx * 16 + arow;
        async_load16((const char*)A + ((size_t)row * K + ko) * 2 + acolb,
                     (char*)&As[b][0] + idx * 1024);
      } else {
        int row = bn + (idx - 8) * 16 + arow;
        async_load16((const char*)Bt + ((size_t)row * K + ko) * 2 + acolb,
                     (char*)&Bs[b][0] + (idx - 8) * 1024);
      }
    }
  };

  stage(0, 0);
  __syncthreads();
  for (int t = 0; t < 32; t++) {
    const int cur = t & 1;
    if (t + 1 < 32) stage(cur ^ 1, (t + 1) << 5);
    short8 af[4], bfr[4];
#pragma unroll
    for (int i = 0; i < 4; i++) {
      af[i] = *(const short8*)&As[cur][(wm + i * 16 + llo) * 32 + lhi * 8];
      bfr[i] = *(const short8*)&Bs[cur][(wn + i * 16 + llo) * 32 + lhi * 8];
    }
#pragma unroll
    for (int mi = 0; mi < 4; mi++)
#pragma unroll
      for (int ni = 0; ni < 4; ni++)
        acc[mi][ni] = __builtin_amdgcn_mfma_f32_16x16x32_bf16(af[mi], bfr[ni],
                                                              acc[mi][ni], 0, 0, 0);
    __syncthreads();
  }

#pragma unroll
  for (int mi = 0; mi < 4; mi++)
#pragma unroll
    for (int ni = 0; ni < 4; ni++) {
      int row0 = bm + wm + mi * 16 + lhi * 4;
      int col = bn + wn + ni * 16 + llo;
      int seg = col >> 10, c = col & 1023;
      u16* dst = (seg == 0) ? qbb : (seg == 1) ? kbb : vbb;
      float bb = (seg == 0) ? bq[c] : (seg == 1) ? bk[c] : bv[c];
#pragma unroll
      for (int r = 0; r < 4; r++)
        dst[(size_t)(row0 + r) * 1024 + c] = f2bf(acc[mi][ni][r] + bb);
    }
}

// ---------- scores GEMM (hi/lo 3-term) + fused argmax -> bucket ----------
// A=x (hi/lo) [2048x1024], B=Wqpt (hi/lo) [512x1024]; BM=32, BN=128
__global__ __launch_bounds__(256) void score_argmax_kernel(
    const u16* __restrict__ A0, const u16* __restrict__ A1,
    const u16* __restrict__ B0, const u16* __restrict__ B1,
    const float* __restrict__ bias_sc, int* __restrict__ bucket) {
  const int K = 1024;
  // per-buf u16 layout: Ah[0,1024) Al[1024,2048) Bh[2048,6144) Bl[6144,10240)
  __shared__ __align__(16) u16 S[2][10240];
  const int tid = threadIdx.x;
  const int wave = tid >> 6, lane = tid & 63;
  const int lhi = lane >> 4, llo = lane & 15;
  const int bid = xcd_swz(blockIdx.x, gridDim.x);
  const int bm = (bid >> 2) << 5;       // 64 row tiles
  const int bn = (bid & 3) << 7;        // 4 col tiles of 128
  const int wm = (wave & 1) * 16;
  const int wn = (wave >> 1) * 64;
  const int arow = lane >> 2;
  const int acolb = (lane & 3) * 16;

  float4v acc[4];
#pragma unroll
  for (int ni = 0; ni < 4; ni++)
#pragma unroll
    for (int r = 0; r < 4; r++) acc[ni][r] = 0.f;

  auto stage = [&](int b, int ko) {
    char* base = (char*)&S[b][0];
#pragma unroll
    for (int cc = 0; cc < 5; cc++) {
      int idx = wave * 5 + cc;  // 0..19
      const u16* src;
      int row;
      char* dst;
      if (idx < 2) {
        src = A0; row = bm + idx * 16 + arow; dst = base + idx * 1024;
      } else if (idx < 4) {
        src = A1; row = bm + (idx - 2) * 16 + arow; dst = base + 2048 + (idx - 2) * 1024;
      } else if (idx < 12) {
        src = B0; row = bn + (idx - 4) * 16 + arow; dst = base + 4096 + (idx - 4) * 1024;
      } else {
        src = B1; row = bn + (idx - 12) * 16 + arow; dst = base + 12288 + (idx - 12) * 1024;
      }
      async_load16((const char*)src + ((size_t)row * K + ko) * 2 + acolb, dst);
    }
  };

  stage(0, 0);
  __syncthreads();
  for (int t = 0; t < 32; t++) {
    const int cur = t & 1;
    if (t + 1 < 32) stage(cur ^ 1, (t + 1) << 5);
    const u16* Sc = &S[cur][0];
    short8 afh, afl, bfh[4], bfl[4];
    afh = *(const short8*)&Sc[(wm + llo) * 32 + lhi * 8];
    afl = *(const short8*)&Sc[1024 + (wm + llo) * 32 + lhi * 8];
#pragma unroll
    for (int i = 0; i < 4; i++) {
      bfh[i] = *(const short8*)&Sc[2048 + (wn + i * 16 + llo) * 32 + lhi * 8];
      bfl[i] = *(const short8*)&Sc[6144 + (wn + i * 16 + llo) * 32 + lhi * 8];
    }
#pragma unroll
    for (int ni = 0; ni < 4; ni++)
      acc[ni] = __builtin_amdgcn_mfma_f32_16x16x32_bf16(afh, bfh[ni], acc[ni], 0, 0, 0);
#pragma unroll
    for (int ni = 0; ni < 4; ni++)
      acc[ni] = __builtin_amdgcn_mfma_f32_16x16x32_bf16(afh, bfl[ni], acc[ni], 0, 0, 0);
#pragma unroll
    for (int ni = 0; ni < 4; ni++)
      acc[ni] = __builtin_amdgcn_mfma_f32_16x16x32_bf16(afl, bfh[ni], acc[ni], 0, 0, 0);
    __syncthreads();
  }

  // argmax epilogue: wave's 64 cols = one head's buckets
  const int head = (bn + wn) >> 6;
  float bsc[4];
#pragma unroll
  for (int ni = 0; ni < 4; ni++) bsc[ni] = bias_sc[head * 64 + ni * 16 + llo];
#pragma unroll
  for (int r = 0; r < 4; r++) {
    float bv = acc[0][r] + bsc[0];
    int bi = llo;
#pragma unroll
    for (int ni = 1; ni < 4; ni++) {
      float v = acc[ni][r] + bsc[ni];
      if (v > bv) { bv = v; bi = ni * 16 + llo; }
    }
#pragma unroll
    for (int o = 1; o < 16; o <<= 1) {
      float ov = __shfl_xor(bv, o);
      int oi = __shfl_xor(bi, o);
      if (ov > bv || (ov == bv && oi < bi)) { bv = ov; bi = oi; }
    }
    if (llo == 0) bucket[head * N_TOK + bm + wm + lhi * 4 + r] = bi;
  }
}

// ---------- fused sort: counts + scan + worklist + stable perm fill ----------
__device__ __forceinline__ unsigned long long match_mask(int b) {
  unsigned long long mask = ~0ull;
#pragma unroll
  for (int bit = 0; bit < 6; bit++) {
    unsigned long long vt = __ballot((b >> bit) & 1);
    mask &= ((b >> bit) & 1) ? vt : ~vt;
  }
  return mask;
}

__global__ __launch_bounds__(512) void sort_kernel(
    const int* __restrict__ bucket, int* __restrict__ counts_g,
    int* __restrict__ offsets_g, int* __restrict__ perm,
    int* __restrict__ wl, int* __restrict__ wl_count) {
  __shared__ int cnt[512];
  __shared__ int sc[512];
  __shared__ int run[512];
  const int tid = threadIdx.x;
  const int w = tid >> 6, lane = tid & 63;
  cnt[tid] = 0;
  __syncthreads();
  // phase 1: counts (wave w = head w)
  for (int t = 0; t < N_TOK; t += 64) {
    int b = bucket[w * N_TOK + t + lane];
    unsigned long long mask = match_mask(b);
    if (lane == __ffsll(mask) - 1) cnt[w * 64 + b] += __popcll(mask);
  }
  __syncthreads();
  // phase 2a: scan counts -> offsets
  int c = cnt[tid];
  sc[tid] = c;
  __syncthreads();
  for (int o = 1; o < 512; o <<= 1) {
    int v = (tid >= o) ? sc[tid - o] : 0;
    __syncthreads();
    sc[tid] += v;
    __syncthreads();
  }
  int off0 = sc[tid] - c;
  offsets_g[tid] = off0;
  counts_g[tid] = c;
  run[tid] = off0;
  __syncthreads();
  // phase 2b: scan qtiles -> worklist
  int nq = (c + 15) >> 4;
  sc[tid] = nq;
  __syncthreads();
  for (int o = 1; o < 512; o <<= 1) {
    int v = (tid >= o) ? sc[tid - o] : 0;
    __syncthreads();
    sc[tid] += v;
    __syncthreads();
  }
  int base = sc[tid] - nq;
  int hh = tid >> 6, bb = tid & 63;
  for (int i = 0; i < nq; i++) wl[base + i] = (hh << 13) | (bb << 7) | i;
  if (tid == 511) wl_count[0] = sc[511];
  __syncthreads();
  // phase 3: stable fill (ascending token order per head)
  for (int t = 0; t < N_TOK; t += 64) {
    int tok = t + lane;
    int b = bucket[w * N_TOK + tok];
    unsigned long long mask = match_mask(b);
    int lower = __popcll(mask & ((1ull << lane) - 1ull));
    int pos = run[w * 64 + b] + lower;
    perm[pos] = tok;
    if (lane == __ffsll(mask) - 1) run[w * 64 + b] += __popcll(mask);
  }
}

// ---------- gather-transpose V ----------
__global__ __launch_bounds__(256) void gather_vt_kernel(
    const u16* __restrict__ vbb, const int* __restrict__ perm,
    u16* __restrict__ Vts) {
  __shared__ u16 lds[64][72];
  int bid = blockIdx.x;
  int h = bid >> 6;
  int ptile = (bid & 63) >> 1;
  int d0 = (bid & 1) * 64;
  int pos0 = ptile * 64;
  int t = threadIdx.x;
#pragma unroll
  for (int i = 0; i < 2; i++) {
    int unit = t + 256 * i;
    int p = unit >> 3, seg = unit & 7;
    int tok = perm[h * N_TOK + pos0 + p];
    short8 v = *(const short8*)&vbb[(size_t)tok * D_MODEL + h * HDIM + d0 + seg * 8];
    *(short8*)&lds[p][seg * 8] = v;
  }
  __syncthreads();
#pragma unroll
  for (int i = 0; i < 8; i++) {
    int unit = t + 256 * i;
    int drow = unit >> 5, pp = unit & 31;
    uint32_t val = (uint32_t)lds[2 * pp][drow] |
                   ((uint32_t)lds[2 * pp + 1][drow] << 16);
    uint32_t* dst = (uint32_t*)&Vts[(size_t)(h * HDIM + d0 + drow) * N_TOK + pos0];
    dst[pp] = val;
  }
}

// ---------- per-bucket attention ----------
__global__ __launch_bounds__(256) void attn_bucket_kernel(
    const u16* __restrict__ qbb, const u16* __restrict__ kbb,
    const u16* __restrict__ Vts, const int* __restrict__ perm,
    const int* __restrict__ offsets, const int* __restrict__ counts,
    const int* __restrict__ wl, const int* __restrict__ wl_count,
    u16* __restrict__ ob) {
  const int wave = threadIdx.x >> 6, lane = threadIdx.x & 63;
  const int lhi = lane >> 4, llo = lane & 15;
  const int wslot = blockIdx.x * 4 + wave;
  const int NW = ATTN_BLOCKS * 4;
  const int cnt = wl_count[0];
  __shared__ __align__(16) u16 P_lds[4][16][64];
  const float scale = 0.08838834764831845f;

  for (int e = wslot; e < cnt; e += NW) {
    int ent = wl[e];
    int h = ent >> 13, qt = ent & 127;
    int hb = (h << 6) | ((ent >> 7) & 63);
    int off = offsets[hb];
    int bs = counts[hb];
    int offh = off - h * N_TOK;
    int qbase = qt * 16;

    int qr = qbase + llo;
    int tokq = perm[off + min(qr, bs - 1)];
    const u16* qrow = &qbb[(size_t)tokq * D_MODEL + h * HDIM];
    short8 qf[4];
#pragma unroll
    for (int kf = 0; kf < 4; kf++)
      qf[kf] = *(const short8*)&qrow[kf * 32 + lhi * 8];

    float m[4], l[4];
#pragma unroll
    for (int r = 0; r < 4; r++) { m[r] = -INFINITY; l[r] = 0.f; }
    float4v accO[8];
#pragma unroll
    for (int d = 0; d < 8; d++)
#pragma unroll
      for (int r = 0; r < 4; r++) accO[d][r] = 0.f;

    for (int c0 = 0; c0 < bs; c0 += 64) {
      float4v scv[4];
#pragma unroll
      for (int nf = 0; nf < 4; nf++)
#pragma unroll
        for (int r = 0; r < 4; r++) scv[nf][r] = 0.f;
#pragma unroll
      for (int nf = 0; nf < 4; nf++) {
        int kcol = c0 + nf * 16 + llo;
        int tokk = perm[off + min(kcol, bs - 1)];
        const u16* krow = &kbb[(size_t)tokk * D_MODEL + h * HDIM];
#pragma unroll
        for (int kf = 0; kf < 4; kf++) {
          short8 kfr = *(const short8*)&krow[kf * 32 + lhi * 8];
          scv[nf] = __builtin_amdgcn_mfma_f32_16x16x32_bf16(qf[kf], kfr, scv[nf], 0, 0, 0);
        }
      }

      float tmax[4];
#pragma unroll
      for (int r = 0; r < 4; r++) tmax[r] = -INFINITY;
#pragma unroll
      for (int nf = 0; nf < 4; nf++) {
        bool valid = (c0 + nf * 16 + llo) < bs;
#pragma unroll
        for (int r = 0; r < 4; r++) {
          float v = valid ? scv[nf][r] * scale : -1e30f;
          scv[nf][r] = v;
          tmax[r] = fmaxf(tmax[r], v);
        }
      }
#pragma unroll
      for (int r = 0; r < 4; r++)
#pragma unroll
        for (int o = 1; o < 16; o <<= 1)
          tmax[r] = fmaxf(tmax[r], __shfl_xor(tmax[r], o));

      float resc[4], psum[4];
#pragma unroll
      for (int r = 0; r < 4; r++) {
        float mn = fmaxf(m[r], tmax[r]);
        resc[r] = __expf(m[r] - mn);
        m[r] = mn;
        psum[r] = 0.f;
      }
#pragma unroll
      for (int nf = 0; nf < 4; nf++)
#pragma unroll
        for (int r = 0; r < 4; r++) {
          float p = __expf(scv[nf][r] - m[r]);
          psum[r] += p;
          P_lds[wave][lhi * 4 + r][nf * 16 + llo] = f2bf(p);
        }
#pragma unroll
      for (int r = 0; r < 4; r++) {
#pragma unroll
        for (int o = 1; o < 16; o <<= 1) psum[r] += __shfl_xor(psum[r], o);
        l[r] = l[r] * resc[r] + psum[r];
      }
#pragma unroll
      for (int d = 0; d < 8; d++)
#pragma unroll
        for (int r = 0; r < 4; r++) accO[d][r] *= resc[r];

      asm volatile("s_waitcnt lgkmcnt(0)" ::: "memory");
      short8 pf[2];
#pragma unroll
      for (int k2 = 0; k2 < 2; k2++)
        pf[k2] = *(const short8*)&P_lds[wave][llo][k2 * 32 + lhi * 8];
#pragma unroll
      for (int d = 0; d < 8; d++)
#pragma unroll
        for (int k2 = 0; k2 < 2; k2++) {
          short8 vfr = *(const short8*)&Vts[(size_t)(h * HDIM + d * 16 + llo) * N_TOK +
                                            offh + c0 + k2 * 32 + lhi * 8];
          accO[d] = __builtin_amdgcn_mfma_f32_16x16x32_bf16(pf[k2], vfr, accO[d], 0, 0, 0);
        }
      asm volatile("" ::: "memory");
    }

#pragma unroll
    for (int r = 0; r < 4; r++) {
      int rl = qbase + lhi * 4 + r;
      if (rl < bs) {
        int tok = perm[off + rl];
        float inv = 1.f / l[r];
#pragma unroll
        for (int d = 0; d < 8; d++)
          ob[(size_t)tok * D_MODEL + h * HDIM + d * 16 + llo] = f2bf(accO[d][r] * inv);
      }
    }
  }
}

// ---------- O-projection GEMM: out = ob * wot^T + bo (f32 out) ----------
__global__ __launch_bounds__(256) void gemm_out_kernel(
    const u16* __restrict__ A, const u16* __restrict__ Bt,
    float* __restrict__ C, const float* __restrict__ bias) {
  const int K = 1024, N = 1024;
  __shared__ __align__(16) u16 As[2][64 * 32];
  __shared__ __align__(16) u16 Bs[2][128 * 32];
  const int tid = threadIdx.x;
  const int wave = tid >> 6, lane = tid & 63;
  const int lhi = lane >> 4, llo = lane & 15;
  const int bid = xcd_swz(blockIdx.x, gridDim.x);
  const int bm = (bid >> 3) * 64;
  const int bn = (bid & 7) << 7;
  const int wm = (wave & 1) * 32;
  const int wn = (wave >> 1) * 64;
  const int arow = lane >> 2;
  const int acolb = (lane & 3) * 16;

  float4v acc[2][4];
#pragma unroll
  for (int mi = 0; mi < 2; mi++)
#pragma unroll
    for (int ni = 0; ni < 4; ni++)
#pragma unroll
      for (int r = 0; r < 4; r++) acc[mi][ni][r] = 0.f;

  auto stage = [&](int b, int ko) {
#pragma unroll
    for (int cc = 0; cc < 3; cc++) {
      int idx = wave * 3 + cc;  // 0..11
      if (idx < 4) {
        int row = bm + idx * 16 + arow;
        async_load16((const char*)A + ((size_t)row * K + ko) * 2 + acolb,
                     (char*)&As[b][0] + idx * 1024);
      } else {
        int row = bn + (idx - 4) * 16 + arow;
        async_load16((const char*)Bt + ((size_t)row * K + ko) * 2 + acolb,
                     (char*)&Bs[b][0] + (idx - 4) * 1024);
      }
    }
  };

  stage(0, 0);
  __syncthreads();
  for (int t = 0; t < 32; t++) {
    const int cur = t & 1;
    if (t + 1 < 32) stage(cur ^ 1, (t + 1) << 5);
    short8 af[2], bfr[4];
#pragma unroll
    for (int i = 0; i < 2; i++)
      af[i] = *(const short8*)&As[cur][(wm + i * 16 + llo) * 32 + lhi * 8];
#pragma unroll
    for (int i = 0; i < 4; i++)
      bfr[i] = *(const short8*)&Bs[cur][(wn + i * 16 + llo) * 32 + lhi * 8];
#pragma unroll
    for (int mi = 0; mi < 2; mi++)
#pragma unroll
      for (int ni = 0; ni < 4; ni++)
        acc[mi][ni] = __builtin_amdgcn_mfma_f32_16x16x32_bf16(af[mi], bfr[ni],
                                                              acc[mi][ni], 0, 0, 0);
    __syncthreads();
  }

#pragma unroll
  for (int mi = 0; mi < 2; mi++)
#pragma unroll
    for (int ni = 0; ni < 4; ni++) {
      int row0 = bm + wm + mi * 16 + lhi * 4;
      int col = bn + wn + ni * 16 + llo;
      float bb = bias[col];
#pragma unroll
      for (int r = 0; r < 4; r++)
        C[(size_t)(row0 + r) * N + col] = acc[mi][ni][r] + bb;
    }
}

extern "C" void kernel_launch(void* const* d_in, const int* in_sizes, int n_in,
                              void* d_out, int out_size, void* d_ws, size_t ws_size,
                              hipStream_t stream) {
  const float* x  = (const float*)d_in[0];
  const float* Wq = (const float*)d_in[1];
  const float* bq = (const float*)d_in[2];
  const float* Wk = (const float*)d_in[3];
  const float* bk = (const float*)d_in[4];
  const float* Wv = (const float*)d_in[5];
  const float* bv = (const float*)d_in[6];
  const float* Wo = (const float*)d_in[7];
  const float* bo = (const float*)d_in[8];
  const float* hp = (const float*)d_in[9];
  float* out = (float*)d_out;

  char* ws = (char*)d_ws;
  size_t off = 0;
  auto alloc = [&](size_t b) {
    char* p = ws + off;
    off += (b + 255) & ~(size_t)255;
    return p;
  };

  const int N = N_TOK, D = D_MODEL;
  u16* xhi     = (u16*)alloc((size_t)N * D * 2);
  u16* xlo     = (u16*)alloc((size_t)N * D * 2);
  u16* qkvt    = (u16*)alloc((size_t)3 * D * D * 2);
  u16* wot     = (u16*)alloc((size_t)D * D * 2);
  u16* Wqpt_hi = (u16*)alloc((size_t)512 * D * 2);
  u16* Wqpt_lo = (u16*)alloc((size_t)512 * D * 2);
  float* biasc = (float*)alloc(512 * 4);
  u16* qbb     = (u16*)alloc((size_t)N * D * 2);
  u16* kbb     = (u16*)alloc((size_t)N * D * 2);
  u16* vbb     = (u16*)alloc((size_t)N * D * 2);
  u16* Vts     = (u16*)alloc((size_t)N_HEAD * HDIM * N * 2 + 256);
  int* bucket  = (int*)alloc((size_t)N_HEAD * N * 4);
  int* counts  = (int*)alloc(512 * 4);
  int* offs    = (int*)alloc(512 * 4);
  int* perm    = (int*)alloc((size_t)N_HEAD * N * 4);
  int* wl      = (int*)alloc(WL_CAP * 4);
  int* wlcnt   = (int*)alloc(256);
  u16* ob      = (u16*)alloc((size_t)N * D * 2);

  const int nelem = N * D;

  split_cast_kernel<<<(nelem + 255) / 256, 256, 0, stream>>>(x, xhi, xlo, nelem);
  transpose_all_kernel<<<dim3(32, 32, 4), 256, 0, stream>>>(Wq, Wk, Wv, Wo, qkvt, wot);
  wqp_build_kernel<<<dim3(16, 8), 256, 0, stream>>>(Wq, hp, bq, Wqpt_hi, Wqpt_lo, biasc);

  qkv_gemm_kernel<<<384, 256, 0, stream>>>(xhi, qkvt, bq, bk, bv, qbb, kbb, vbb);
  score_argmax_kernel<<<256, 256, 0, stream>>>(xhi, xlo, Wqpt_hi, Wqpt_lo, biasc, bucket);

  sort_kernel<<<1, 512, 0, stream>>>(bucket, counts, offs, perm, wl, wlcnt);
  gather_vt_kernel<<<512, 256, 0, stream>>>(vbb, perm, Vts);

  attn_bucket_kernel<<<ATTN_BLOCKS, 256, 0, stream>>>(
      qbb, kbb, Vts, perm, offs, counts, wl, wlcnt, ob);

  gemm_out_kernel<<<256, 256, 0, stream>>>(ob, wot, out, bo);

  (void)in_sizes; (void)n_in; (void)out_size; (void)ws_size;
}

// Round 6
// 146.766 us; speedup vs baseline: 1.0994x; 1.0994x over previous
//
#include <hip/hip_runtime.h>
#include <stdint.h>

typedef __attribute__((ext_vector_type(8))) short short8;
typedef __attribute__((ext_vector_type(4))) short short4v;
typedef __attribute__((ext_vector_type(4))) float float4v;
typedef unsigned short u16;

#define N_TOK 2048
#define D_MODEL 1024
#define N_HEAD 8
#define HDIM 128
#define N_BUCKET 64
#define WL_CAP 2048
#define ATTN_BLOCKS 384

__device__ __forceinline__ u16 f2bf(float f) {
  uint32_t u = __float_as_uint(f);
  uint32_t r = u + 0x7fffu + ((u >> 16) & 1u);
  return (u16)(r >> 16);
}
__device__ __forceinline__ float bf2f(u16 h) {
  return __uint_as_float(((uint32_t)h) << 16);
}

__device__ __forceinline__ void async_load16(const void* g, void* l) {
  __builtin_amdgcn_global_load_lds(
      (const __attribute__((address_space(1))) void*)g,
      (__attribute__((address_space(3))) void*)l, 16, 0, 0);
}

__device__ __forceinline__ int xcd_swz(int bid, int nwg) {
  return (bid & 7) * (nwg >> 3) + (bid >> 3);
}

// ---------- prep: transpose 4 weight matrices (z=0..3) + split-cast x (z=4) ----
// z=0: Wq -> wqt_hi + wqt_lo; z=1: Wk -> kvt[0:1M]; z=2: Wv -> kvt[1M:2M];
// z=3: Wo -> wot; z=4: x -> xhi + xlo (elementwise, 2048 elems/block)
__global__ __launch_bounds__(256) void prep_kernel(
    const float* __restrict__ x, const float* __restrict__ Wq,
    const float* __restrict__ Wk, const float* __restrict__ Wv,
    const float* __restrict__ Wo, u16* __restrict__ xhi, u16* __restrict__ xlo,
    u16* __restrict__ wqt_hi, u16* __restrict__ wqt_lo, u16* __restrict__ kvt,
    u16* __restrict__ wot) {
  const int z = blockIdx.z;
  if (z == 4) {
    int base = (blockIdx.y * 32 + blockIdx.x) * 2048 + threadIdx.x * 8;
    float4v a = *(const float4v*)&x[base];
    float4v b = *(const float4v*)&x[base + 4];
    short8 hi, lo;
#pragma unroll
    for (int j = 0; j < 4; j++) {
      u16 h = f2bf(a[j]);
      hi[j] = (short)h;
      lo[j] = (short)f2bf(a[j] - bf2f(h));
    }
#pragma unroll
    for (int j = 0; j < 4; j++) {
      u16 h = f2bf(b[j]);
      hi[4 + j] = (short)h;
      lo[4 + j] = (short)f2bf(b[j] - bf2f(h));
    }
    *(short8*)&xhi[base] = hi;
    *(short8*)&xlo[base] = lo;
    return;
  }
  __shared__ float tile[32][33];
  const float* in = (z == 0) ? Wq : (z == 1) ? Wk : (z == 2) ? Wv : Wo;
  u16* hi = (z == 0) ? wqt_hi
            : (z == 1) ? kvt
            : (z == 2) ? (kvt + (size_t)1024 * 1024) : wot;
  u16* lo = (z == 0) ? wqt_lo : nullptr;
  const int C = 1024, R = 1024;
  int c0 = blockIdx.x * 32, r0 = blockIdx.y * 32;
  int tx = threadIdx.x & 31, ty = threadIdx.x >> 5;
#pragma unroll
  for (int i = 0; i < 4; i++) {
    int rl = ty + i * 8;
    tile[rl][tx] = in[(size_t)(r0 + rl) * C + c0 + tx];
  }
  __syncthreads();
#pragma unroll
  for (int i = 0; i < 4; i++) {
    int cl = ty + i * 8;
    float v = tile[tx][cl];
    size_t oidx = (size_t)(c0 + cl) * R + r0 + tx;
    u16 h = f2bf(v);
    hi[oidx] = h;
    if (lo) lo[oidx] = f2bf(v - bf2f(h));
  }
}

// ---------- generic GEMM (BM x 128 tile, BK=32, dbuf prefetch) ----------
template <int BM>
__device__ __forceinline__ void stage_tiles2(const u16* A, const u16* Bt,
                                             u16* As, u16* Bs, int bm, int bn,
                                             int K, int ko, int wave, int lane) {
  const int arow = lane >> 2;
  const int acolb = (lane & 3) * 16;
  constexpr int ACH = BM / 16;
  constexpr int PC = (ACH + 8) / 4;
#pragma unroll
  for (int cc = 0; cc < PC; cc++) {
    int idx = wave * PC + cc;
    if (idx < ACH) {
      int row = idx * 16 + arow;
      const char* g = (const char*)A + ((size_t)(bm + row) * K + ko) * 2 + acolb;
      async_load16(g, (char*)As + idx * 1024);
    } else {
      int row = (idx - ACH) * 16 + arow;
      const char* g = (const char*)Bt + ((size_t)(bn + row) * K + ko) * 2 + acolb;
      async_load16(g, (char*)Bs + (idx - ACH) * 1024);
    }
  }
}

// flags: 2 = add bias, 8 = KV mode (col<1024 -> kbf; col>=1024 -> vbf)
template <int BM>
__global__ __launch_bounds__(256) void gemm_bf16_kernel(
    const u16* __restrict__ A, const u16* __restrict__ Bt,
    float* __restrict__ C, const float* __restrict__ bias,
    const float* __restrict__ bias2, u16* __restrict__ kbf,
    u16* __restrict__ vbf, int N, int K, int flags) {
  constexpr int MI = BM / 32;
  __shared__ __align__(16) u16 As[2][BM * 32];
  __shared__ __align__(16) u16 Bs[2][128 * 32];
  const int tid = threadIdx.x;
  const int wave = tid >> 6, lane = tid & 63;
  const int lhi = lane >> 4, llo = lane & 15;
  const int nbn = N >> 7;
  const int bid = xcd_swz(blockIdx.x, gridDim.x);
  const int bm = (bid / nbn) * BM;
  const int bn = (bid % nbn) << 7;
  const int wm = (BM == 128) ? (wave >> 1) * 64 : (wave & 1) * 32;
  const int wn = (BM == 128) ? (wave & 1) * 64 : (wave >> 1) * 64;

  float4v acc[MI][4];
#pragma unroll
  for (int mi = 0; mi < MI; mi++)
#pragma unroll
    for (int ni = 0; ni < 4; ni++)
#pragma unroll
      for (int r = 0; r < 4; r++) acc[mi][ni][r] = 0.f;

  stage_tiles2<BM>(A, Bt, As[0], Bs[0], bm, bn, K, 0, wave, lane);
  __syncthreads();
  const int nk = K >> 5;
  for (int t = 0; t < nk; t++) {
    const int cur = t & 1;
    if (t + 1 < nk)
      stage_tiles2<BM>(A, Bt, As[cur ^ 1], Bs[cur ^ 1], bm, bn, K,
                       (t + 1) << 5, wave, lane);
    short8 af[MI], bfr[4];
#pragma unroll
    for (int i = 0; i < MI; i++)
      af[i] = *(const short8*)&As[cur][(wm + i * 16 + llo) * 32 + lhi * 8];
#pragma unroll
    for (int i = 0; i < 4; i++)
      bfr[i] = *(const short8*)&Bs[cur][(wn + i * 16 + llo) * 32 + lhi * 8];
#pragma unroll
    for (int mi = 0; mi < MI; mi++)
#pragma unroll
      for (int ni = 0; ni < 4; ni++)
        acc[mi][ni] = __builtin_amdgcn_mfma_f32_16x16x32_bf16(af[mi], bfr[ni],
                                                              acc[mi][ni], 0, 0, 0);
    __syncthreads();
  }

#pragma unroll
  for (int mi = 0; mi < MI; mi++)
#pragma unroll
    for (int ni = 0; ni < 4; ni++) {
      int row0 = bm + wm + mi * 16 + lhi * 4;
      int col = bn + wn + ni * 16 + llo;
      if (flags & 8) {
        u16* dst = (col < 1024) ? kbf : vbf;
        int c = col & 1023;
        float bb = (col < 1024) ? bias[c] : bias2[c];
#pragma unroll
        for (int r = 0; r < 4; r++)
          dst[(size_t)(row0 + r) * 1024 + c] = f2bf(acc[mi][ni][r] + bb);
      } else {
        float bb = (flags & 2) ? bias[col] : 0.f;
        float* cp = C + (size_t)row0 * N + col;
#pragma unroll
        for (int r = 0; r < 4; r++) cp[(size_t)r * N] = acc[mi][ni][r] + bb;
      }
    }
}

// ---------- Q GEMM: interleaved hi/lo compensated, single K-walk ----------
__global__ __launch_bounds__(256) void gemm3_bf16_kernel(
    const u16* __restrict__ A0, const u16* __restrict__ A1,
    const u16* __restrict__ B0, const u16* __restrict__ B1,
    float* __restrict__ C, const float* __restrict__ bias,
    u16* __restrict__ bf_out, int N, int K) {
  constexpr int MI = 2;  // BM=64, BN=128
  __shared__ __align__(16) u16 S3[2][12288];
  const int tid = threadIdx.x;
  const int wave = tid >> 6, lane = tid & 63;
  const int lhi = lane >> 4, llo = lane & 15;
  const int nbn = N >> 7;
  const int bid = xcd_swz(blockIdx.x, gridDim.x);
  const int bm = (bid / nbn) * 64;
  const int bn = (bid % nbn) << 7;
  const int wm = (wave & 1) * 32;
  const int wn = (wave >> 1) * 64;
  const int arow = lane >> 2;
  const int acolb = (lane & 3) * 16;

  float4v acc[MI][4];
#pragma unroll
  for (int mi = 0; mi < MI; mi++)
#pragma unroll
    for (int ni = 0; ni < 4; ni++)
#pragma unroll
      for (int r = 0; r < 4; r++) acc[mi][ni][r] = 0.f;

  auto stage = [&](int b, int ko) {
    char* base = (char*)&S3[b][0];
#pragma unroll
    for (int cc = 0; cc < 6; cc++) {
      int idx = wave * 6 + cc;  // 0..23
      const u16* src;
      int row;
      char* dst;
      if (idx < 4) {
        src = A0; row = bm + idx * 16 + arow; dst = base + idx * 1024;
      } else if (idx < 8) {
        src = A1; row = bm + (idx - 4) * 16 + arow; dst = base + 4096 + (idx - 4) * 1024;
      } else if (idx < 16) {
        src = B0; row = bn + (idx - 8) * 16 + arow; dst = base + 8192 + (idx - 8) * 1024;
      } else {
        src = B1; row = bn + (idx - 16) * 16 + arow; dst = base + 16384 + (idx - 16) * 1024;
      }
      async_load16((const char*)src + ((size_t)row * K + ko) * 2 + acolb, dst);
    }
  };

  stage(0, 0);
  __syncthreads();
  const int nk = K >> 5;
  for (int t = 0; t < nk; t++) {
    const int cur = t & 1;
    if (t + 1 < nk) stage(cur ^ 1, (t + 1) << 5);
    const u16* Sc = &S3[cur][0];
    short8 afh[MI], afl[MI], bfh[4], bfl[4];
#pragma unroll
    for (int i = 0; i < MI; i++) {
      afh[i] = *(const short8*)&Sc[(wm + i * 16 + llo) * 32 + lhi * 8];
      afl[i] = *(const short8*)&Sc[2048 + (wm + i * 16 + llo) * 32 + lhi * 8];
    }
#pragma unroll
    for (int i = 0; i < 4; i++) {
      bfh[i] = *(const short8*)&Sc[4096 + (wn + i * 16 + llo) * 32 + lhi * 8];
      bfl[i] = *(const short8*)&Sc[8192 + (wn + i * 16 + llo) * 32 + lhi * 8];
    }
#pragma unroll
    for (int mi = 0; mi < MI; mi++)
#pragma unroll
      for (int ni = 0; ni < 4; ni++)
        acc[mi][ni] = __builtin_amdgcn_mfma_f32_16x16x32_bf16(afh[mi], bfh[ni],
                                                              acc[mi][ni], 0, 0, 0);
#pragma unroll
    for (int mi = 0; mi < MI; mi++)
#pragma unroll
      for (int ni = 0; ni < 4; ni++)
        acc[mi][ni] = __builtin_amdgcn_mfma_f32_16x16x32_bf16(afh[mi], bfl[ni],
                                                              acc[mi][ni], 0, 0, 0);
#pragma unroll
    for (int mi = 0; mi < MI; mi++)
#pragma unroll
      for (int ni = 0; ni < 4; ni++)
        acc[mi][ni] = __builtin_amdgcn_mfma_f32_16x16x32_bf16(afl[mi], bfh[ni],
                                                              acc[mi][ni], 0, 0, 0);
    __syncthreads();
  }

#pragma unroll
  for (int mi = 0; mi < MI; mi++)
#pragma unroll
    for (int ni = 0; ni < 4; ni++) {
      int row0 = bm + wm + mi * 16 + lhi * 4;
      int col = bn + wn + ni * 16 + llo;
      float bb = bias[col];
#pragma unroll
      for (int r = 0; r < 4; r++) {
        float v = acc[mi][ni][r] + bb;
        C[(size_t)(row0 + r) * N + col] = v;
        bf_out[(size_t)(row0 + r) * N + col] = f2bf(v);
      }
    }
}

// ---------- hash scores + argmax (LDS-tiled) ----------
__global__ __launch_bounds__(256) void hash_argmax_kernel(
    const float* __restrict__ Qf, const float* __restrict__ proj,
    int* __restrict__ bucket) {
  __shared__ float sQ[64 * 128];   // 32 KB
  __shared__ float sP[128 * 64];   // 32 KB
  const int tid = threadIdx.x;
  const int h = blockIdx.y;
  const int n0 = blockIdx.x * 64;
#pragma unroll
  for (int p = 0; p < 8; p++) {
    int e = p * 1024 + tid * 4;
    int tok = e >> 7, d0 = e & 127;
    float4v v = *(const float4v*)&Qf[(size_t)(n0 + tok) * D_MODEL + h * HDIM + d0];
    int blk = (d0 >> 2) ^ ((tok >> 2) & 7);
    *(float4v*)&sQ[tok * 128 + blk * 4] = v;
  }
#pragma unroll
  for (int p = 0; p < 8; p++) {
    int e = p * 1024 + tid * 4;
    float4v v = *(const float4v*)&proj[(size_t)h * (HDIM * N_BUCKET) + e];
    *(float4v*)&sP[e] = v;
  }
  __syncthreads();

  const int tgrp = tid & 15, fgrp = tid >> 4;
  const int t0 = tgrp * 4, f0 = fgrp * 4;
  float accs[4][4];
#pragma unroll
  for (int i = 0; i < 4; i++)
#pragma unroll
    for (int f = 0; f < 4; f++) accs[i][f] = 0.f;

  for (int d0 = 0; d0 < 128; d0 += 4) {
    int blk = (d0 >> 2) ^ (tgrp & 7);
    float4v qv[4], pv[4];
#pragma unroll
    for (int i = 0; i < 4; i++)
      qv[i] = *(const float4v*)&sQ[(t0 + i) * 128 + blk * 4];
#pragma unroll
    for (int j = 0; j < 4; j++)
      pv[j] = *(const float4v*)&sP[(d0 + j) * 64 + f0];
#pragma unroll
    for (int i = 0; i < 4; i++)
#pragma unroll
      for (int f = 0; f < 4; f++)
        accs[i][f] += qv[i][0] * pv[0][f] + qv[i][1] * pv[1][f] +
                      qv[i][2] * pv[2][f] + qv[i][3] * pv[3][f];
  }

  __syncthreads();
  float* vals = sQ;                       // [64][17]
  int* idxs = (int*)(sQ + 64 * 17);       // [64][17]
#pragma unroll
  for (int i = 0; i < 4; i++) {
    float bv = accs[i][0];
    int bi = f0;
#pragma unroll
    for (int f = 1; f < 4; f++)
      if (accs[i][f] > bv) { bv = accs[i][f]; bi = f0 + f; }
    vals[(t0 + i) * 17 + fgrp] = bv;
    idxs[(t0 + i) * 17 + fgrp] = bi;
  }
  __syncthreads();
  if (tid < 64) {
    float bv = vals[tid * 17];
    int bi = idxs[tid * 17];
#pragma unroll
    for (int g = 1; g < 16; g++) {
      float v = vals[tid * 17 + g];
      int id = idxs[tid * 17 + g];
      if (v > bv || (v == bv && id < bi)) { bv = v; bi = id; }
    }
    bucket[h * N_TOK + n0 + tid] = bi;
  }
}

// ---------- fused sort: counts + scan + worklist + stable perm fill ----------
__device__ __forceinline__ unsigned long long match_mask(int b) {
  unsigned long long mask = ~0ull;
#pragma unroll
  for (int bit = 0; bit < 6; bit++) {
    unsigned long long vt = __ballot((b >> bit) & 1);
    mask &= ((b >> bit) & 1) ? vt : ~vt;
  }
  return mask;
}

__global__ __launch_bounds__(512) void sort_kernel(
    const int* __restrict__ bucket, int* __restrict__ counts_g,
    int* __restrict__ offsets_g, int* __restrict__ perm,
    int* __restrict__ wl, int* __restrict__ wl_count) {
  __shared__ int cnt[512];
  __shared__ int sc[512];
  __shared__ int run[512];
  const int tid = threadIdx.x;
  const int w = tid >> 6, lane = tid & 63;
  cnt[tid] = 0;
  __syncthreads();
  for (int t = 0; t < N_TOK; t += 64) {
    int b = bucket[w * N_TOK + t + lane];
    unsigned long long mask = match_mask(b);
    if (lane == __ffsll(mask) - 1) cnt[w * 64 + b] += __popcll(mask);
  }
  __syncthreads();
  int c = cnt[tid];
  sc[tid] = c;
  __syncthreads();
  for (int o = 1; o < 512; o <<= 1) {
    int v = (tid >= o) ? sc[tid - o] : 0;
    __syncthreads();
    sc[tid] += v;
    __syncthreads();
  }
  int off0 = sc[tid] - c;
  offsets_g[tid] = off0;
  counts_g[tid] = c;
  run[tid] = off0;
  __syncthreads();
  int nq = (c + 15) >> 4;
  sc[tid] = nq;
  __syncthreads();
  for (int o = 1; o < 512; o <<= 1) {
    int v = (tid >= o) ? sc[tid - o] : 0;
    __syncthreads();
    sc[tid] += v;
    __syncthreads();
  }
  int base = sc[tid] - nq;
  int hh = tid >> 6, bb = tid & 63;
  for (int i = 0; i < nq; i++) wl[base + i] = (hh << 13) | (bb << 7) | i;
  if (tid == 511) wl_count[0] = sc[511];
  __syncthreads();
  for (int t = 0; t < N_TOK; t += 64) {
    int tok = t + lane;
    int b = bucket[w * N_TOK + tok];
    unsigned long long mask = match_mask(b);
    int lower = __popcll(mask & ((1ull << lane) - 1ull));
    int pos = run[w * 64 + b] + lower;
    perm[pos] = tok;
    if (lane == __ffsll(mask) - 1) run[w * 64 + b] += __popcll(mask);
  }
}

// ---------- gather-transpose V ----------
__global__ __launch_bounds__(256) void gather_vt_kernel(
    const u16* __restrict__ vbb, const int* __restrict__ perm,
    u16* __restrict__ Vts) {
  __shared__ u16 lds[64][72];
  int bid = blockIdx.x;
  int h = bid >> 6;
  int ptile = (bid & 63) >> 1;
  int d0 = (bid & 1) * 64;
  int pos0 = ptile * 64;
  int t = threadIdx.x;
#pragma unroll
  for (int i = 0; i < 2; i++) {
    int unit = t + 256 * i;
    int p = unit >> 3, seg = unit & 7;
    int tok = perm[h * N_TOK + pos0 + p];
    short8 v = *(const short8*)&vbb[(size_t)tok * D_MODEL + h * HDIM + d0 + seg * 8];
    *(short8*)&lds[p][seg * 8] = v;
  }
  __syncthreads();
#pragma unroll
  for (int i = 0; i < 8; i++) {
    int unit = t + 256 * i;
    int drow = unit >> 5, pp = unit & 31;
    uint32_t val = (uint32_t)lds[2 * pp][drow] |
                   ((uint32_t)lds[2 * pp + 1][drow] << 16);
    uint32_t* dst = (uint32_t*)&Vts[(size_t)(h * HDIM + d0 + drow) * N_TOK + pos0];
    dst[pp] = val;
  }
}

// ---------- per-bucket attention ----------
__global__ __launch_bounds__(256) void attn_bucket_kernel(
    const u16* __restrict__ qbb, const u16* __restrict__ kbb,
    const u16* __restrict__ Vts, const int* __restrict__ perm,
    const int* __restrict__ offsets, const int* __restrict__ counts,
    const int* __restrict__ wl, const int* __restrict__ wl_count,
    u16* __restrict__ ob) {
  const int wave = threadIdx.x >> 6, lane = threadIdx.x & 63;
  const int lhi = lane >> 4, llo = lane & 15;
  const int wslot = blockIdx.x * 4 + wave;
  const int NW = ATTN_BLOCKS * 4;
  const int cnt = wl_count[0];
  __shared__ __align__(16) u16 P_lds[4][16][64];
  const float scale = 0.08838834764831845f;

  for (int e = wslot; e < cnt; e += NW) {
    int ent = wl[e];
    int h = ent >> 13, qt = ent & 127;
    int hb = (h << 6) | ((ent >> 7) & 63);
    int off = offsets[hb];
    int bs = counts[hb];
    int offh = off - h * N_TOK;
    int qbase = qt * 16;

    int qr = qbase + llo;
    int tokq = perm[off + min(qr, bs - 1)];
    const u16* qrow = &qbb[(size_t)tokq * D_MODEL + h * HDIM];
    short8 qf[4];
#pragma unroll
    for (int kf = 0; kf < 4; kf++)
      qf[kf] = *(const short8*)&qrow[kf * 32 + lhi * 8];

    float m[4], l[4];
#pragma unroll
    for (int r = 0; r < 4; r++) { m[r] = -INFINITY; l[r] = 0.f; }
    float4v accO[8];
#pragma unroll
    for (int d = 0; d < 8; d++)
#pragma unroll
      for (int r = 0; r < 4; r++) accO[d][r] = 0.f;

    for (int c0 = 0; c0 < bs; c0 += 64) {
      float4v scv[4];
#pragma unroll
      for (int nf = 0; nf < 4; nf++)
#pragma unroll
        for (int r = 0; r < 4; r++) scv[nf][r] = 0.f;
#pragma unroll
      for (int nf = 0; nf < 4; nf++) {
        int kcol = c0 + nf * 16 + llo;
        int tokk = perm[off + min(kcol, bs - 1)];
        const u16* krow = &kbb[(size_t)tokk * D_MODEL + h * HDIM];
#pragma unroll
        for (int kf = 0; kf < 4; kf++) {
          short8 kfr = *(const short8*)&krow[kf * 32 + lhi * 8];
          scv[nf] = __builtin_amdgcn_mfma_f32_16x16x32_bf16(qf[kf], kfr, scv[nf], 0, 0, 0);
        }
      }

      float tmax[4];
#pragma unroll
      for (int r = 0; r < 4; r++) tmax[r] = -INFINITY;
#pragma unroll
      for (int nf = 0; nf < 4; nf++) {
        bool valid = (c0 + nf * 16 + llo) < bs;
#pragma unroll
        for (int r = 0; r < 4; r++) {
          float v = valid ? scv[nf][r] * scale : -1e30f;
          scv[nf][r] = v;
          tmax[r] = fmaxf(tmax[r], v);
        }
      }
#pragma unroll
      for (int r = 0; r < 4; r++)
#pragma unroll
        for (int o = 1; o < 16; o <<= 1)
          tmax[r] = fmaxf(tmax[r], __shfl_xor(tmax[r], o));

      float resc[4], psum[4];
#pragma unroll
      for (int r = 0; r < 4; r++) {
        float mn = fmaxf(m[r], tmax[r]);
        resc[r] = __expf(m[r] - mn);
        m[r] = mn;
        psum[r] = 0.f;
      }
#pragma unroll
      for (int nf = 0; nf < 4; nf++)
#pragma unroll
        for (int r = 0; r < 4; r++) {
          float p = __expf(scv[nf][r] - m[r]);
          psum[r] += p;
          P_lds[wave][lhi * 4 + r][nf * 16 + llo] = f2bf(p);
        }
#pragma unroll
      for (int r = 0; r < 4; r++) {
#pragma unroll
        for (int o = 1; o < 16; o <<= 1) psum[r] += __shfl_xor(psum[r], o);
        l[r] = l[r] * resc[r] + psum[r];
      }
#pragma unroll
      for (int d = 0; d < 8; d++)
#pragma unroll
        for (int r = 0; r < 4; r++) accO[d][r] *= resc[r];

      asm volatile("s_waitcnt lgkmcnt(0)" ::: "memory");
      short8 pf[2];
#pragma unroll
      for (int k2 = 0; k2 < 2; k2++)
        pf[k2] = *(const short8*)&P_lds[wave][llo][k2 * 32 + lhi * 8];
#pragma unroll
      for (int d = 0; d < 8; d++)
#pragma unroll
        for (int k2 = 0; k2 < 2; k2++) {
          short8 vfr = *(const short8*)&Vts[(size_t)(h * HDIM + d * 16 + llo) * N_TOK +
                                            offh + c0 + k2 * 32 + lhi * 8];
          accO[d] = __builtin_amdgcn_mfma_f32_16x16x32_bf16(pf[k2], vfr, accO[d], 0, 0, 0);
        }
      asm volatile("" ::: "memory");
    }

#pragma unroll
    for (int r = 0; r < 4; r++) {
      int rl = qbase + lhi * 4 + r;
      if (rl < bs) {
        int tok = perm[off + rl];
        float inv = 1.f / l[r];
#pragma unroll
        for (int d = 0; d < 8; d++)
          ob[(size_t)tok * D_MODEL + h * HDIM + d * 16 + llo] = f2bf(accO[d][r] * inv);
      }
    }
  }
}

extern "C" void kernel_launch(void* const* d_in, const int* in_sizes, int n_in,
                              void* d_out, int out_size, void* d_ws, size_t ws_size,
                              hipStream_t stream) {
  const float* x  = (const float*)d_in[0];
  const float* Wq = (const float*)d_in[1];
  const float* bq = (const float*)d_in[2];
  const float* Wk = (const float*)d_in[3];
  const float* bk = (const float*)d_in[4];
  const float* Wv = (const float*)d_in[5];
  const float* bv = (const float*)d_in[6];
  const float* Wo = (const float*)d_in[7];
  const float* bo = (const float*)d_in[8];
  const float* hp = (const float*)d_in[9];
  float* out = (float*)d_out;

  char* ws = (char*)d_ws;
  size_t off = 0;
  auto alloc = [&](size_t b) {
    char* p = ws + off;
    off += (b + 255) & ~(size_t)255;
    return p;
  };

  const int N = N_TOK, D = D_MODEL;
  u16* xhi    = (u16*)alloc((size_t)N * D * 2);
  u16* xlo    = (u16*)alloc((size_t)N * D * 2);
  u16* wqt_hi = (u16*)alloc((size_t)D * D * 2);
  u16* wqt_lo = (u16*)alloc((size_t)D * D * 2);
  u16* kvt    = (u16*)alloc((size_t)2 * D * D * 2);
  u16* wot    = (u16*)alloc((size_t)D * D * 2);
  float* Qf   = (float*)alloc((size_t)N * D * 4);
  u16* qbb    = (u16*)alloc((size_t)N * D * 2);
  u16* kbb    = (u16*)alloc((size_t)N * D * 2);
  u16* vbb    = (u16*)alloc((size_t)N * D * 2);
  u16* Vts    = (u16*)alloc((size_t)N_HEAD * HDIM * N * 2 + 256);
  int* bucket = (int*)alloc((size_t)N_HEAD * N * 4);
  int* counts = (int*)alloc(512 * 4);
  int* offs   = (int*)alloc(512 * 4);
  int* perm   = (int*)alloc((size_t)N_HEAD * N * 4);
  int* wl     = (int*)alloc(WL_CAP * 4);
  int* wlcnt  = (int*)alloc(256);
  u16* ob     = (u16*)alloc((size_t)N * D * 2);

  prep_kernel<<<dim3(32, 32, 5), 256, 0, stream>>>(
      x, Wq, Wk, Wv, Wo, xhi, xlo, wqt_hi, wqt_lo, kvt, wot);

  gemm3_bf16_kernel<<<(N / 64) * (D / 128), 256, 0, stream>>>(
      xhi, xlo, wqt_hi, wqt_lo, Qf, bq, qbb, D, D);
  gemm_bf16_kernel<64><<<(N / 64) * (2 * D / 128), 256, 0, stream>>>(
      xhi, kvt, nullptr, bk, bv, kbb, vbb, 2 * D, D, 2 | 8);

  hash_argmax_kernel<<<dim3(N / 64, N_HEAD), 256, 0, stream>>>(Qf, hp, bucket);
  sort_kernel<<<1, 512, 0, stream>>>(bucket, counts, offs, perm, wl, wlcnt);
  gather_vt_kernel<<<512, 256, 0, stream>>>(vbb, perm, Vts);

  attn_bucket_kernel<<<ATTN_BLOCKS, 256, 0, stream>>>(
      qbb, kbb, Vts, perm, offs, counts, wl, wlcnt, ob);

  gemm_bf16_kernel<64><<<(N / 64) * (D / 128), 256, 0, stream>>>(
      ob, wot, out, bo, nullptr, nullptr, nullptr, D, D, 2);

  (void)in_sizes; (void)n_in; (void)out_size; (void)ws_size;
}